// Round 6
// baseline (2334.684 us; speedup 1.0000x reference)
//
#include <hip/hip_runtime.h>
#include <cstdint>
#include <cstddef>

#define SS 12
#define NN 16384
#define EE 262144
#define TT 3072          // SS*NN/BB

typedef _Float16 h2_t __attribute__((ext_vector_type(2)));
typedef _Float16 f16x8 __attribute__((ext_vector_type(8)));
typedef short bf16x8 __attribute__((ext_vector_type(8)));
typedef float floatx4 __attribute__((ext_vector_type(4)));
typedef unsigned short ushortx8 __attribute__((ext_vector_type(8)));

// ---------- helpers ----------
__device__ __forceinline__ float fast_sig(float x) {
    float e = __builtin_amdgcn_exp2f(-1.442695041f * x);   // exp(-x)
    return __builtin_amdgcn_rcpf(1.f + e);
}
__device__ __forceinline__ float fast_tanh(float x) {
    float e = __builtin_amdgcn_exp2f(2.885390082f * x);    // exp(2x); inf-safe
    return 1.f - 2.f * __builtin_amdgcn_rcpf(e + 1.f);
}
__device__ __forceinline__ unsigned short f2bf(float f) {
    unsigned int x = __float_as_uint(f);
    unsigned int r = (x + 0x7FFFu + ((x >> 16) & 1u)) >> 16;
    return (unsigned short)r;
}
__device__ __forceinline__ float bf2f(unsigned short u) {
    return __uint_as_float(((unsigned int)u) << 16);
}

// ---------- zero counts ----------
__global__ void k_zero(int* __restrict__ p) {
    p[blockIdx.x * 256 + threadIdx.x] = 0;
}

// ---------- CSR build ----------
__global__ void k_count(const int* __restrict__ adj, int* __restrict__ counts) {
    int i = blockIdx.x * 256 + threadIdx.x;          // over SS*EE
    int t = i / EE, e = i - t * EE;
    int dst = adj[(size_t)t * 2 * EE + e];
    atomicAdd(&counts[t * NN + dst], 1);
}

__global__ void k_scan(const int* __restrict__ counts, int* __restrict__ offs,
                       int* __restrict__ cursor) {
    __shared__ int sums[1024];
    int t = blockIdx.x, tid = threadIdx.x;
    const int per = NN / 1024;                       // 16
    int base = t * NN + tid * per;
    int local[16];
    int s = 0;
#pragma unroll
    for (int i = 0; i < per; i++) { local[i] = counts[base + i]; s += local[i]; }
    sums[tid] = s;
    __syncthreads();
    for (int off = 1; off < 1024; off <<= 1) {
        int v = (tid >= off) ? sums[tid - off] : 0;
        __syncthreads();
        sums[tid] += v;
        __syncthreads();
    }
    int run = sums[tid] - s;                         // exclusive
#pragma unroll
    for (int i = 0; i < per; i++) { offs[base + i] = run; cursor[base + i] = run; run += local[i]; }
}

__global__ void k_scatter(const int* __restrict__ adj, const float* __restrict__ vals,
                          int* __restrict__ cursor, int2* __restrict__ edges) {
    int i = blockIdx.x * 256 + threadIdx.x;
    int t = i / EE, e = i - t * EE;
    int dst = adj[(size_t)t * 2 * EE + e];
    int src = adj[(size_t)t * 2 * EE + EE + e];
    float v = vals[(size_t)t * EE + e];
    int p = atomicAdd(&cursor[t * NN + dst], 1);
    edges[(size_t)t * EE + p] = make_int2(src, __float_as_int(v));
}

// ---------- support = xs @ gcn_weight  (fp32 acc, bf16 out) ----------
__global__ __launch_bounds__(256) void k_support(const float* __restrict__ xs,
                                                 const float* __restrict__ W,
                                                 unsigned short* __restrict__ sup) {
    __shared__ float Ash[64][128];
    __shared__ float Wsh[128][128];
    int tid = threadIdx.x;
    size_t rowbase = (size_t)blockIdx.x * 64;
    const float4* xa = (const float4*)(xs + rowbase * 128);
    float4* As = (float4*)&Ash[0][0];
#pragma unroll
    for (int q = 0; q < 8; q++) As[tid + q * 256] = xa[tid + q * 256];
    const float4* wg = (const float4*)W;
    float4* Ws = (float4*)&Wsh[0][0];
#pragma unroll
    for (int q = 0; q < 16; q++) Ws[tid + q * 256] = wg[tid + q * 256];
    __syncthreads();
    int jg = tid & 31, rg = tid >> 5;
    float acc[8][4];
#pragma unroll
    for (int i = 0; i < 8; i++)
#pragma unroll
        for (int j = 0; j < 4; j++) acc[i][j] = 0.f;
    for (int k4 = 0; k4 < 128; k4 += 4) {
        float4 a[8];
#pragma unroll
        for (int i = 0; i < 8; i++) a[i] = *(const float4*)&Ash[rg * 8 + i][k4];
#pragma unroll
        for (int kk = 0; kk < 4; kk++) {
            float4 wv = *(const float4*)&Wsh[k4 + kk][jg * 4];
#pragma unroll
            for (int i = 0; i < 8; i++) {
                float av = (kk == 0) ? a[i].x : (kk == 1) ? a[i].y : (kk == 2) ? a[i].z : a[i].w;
                acc[i][0] += av * wv.x; acc[i][1] += av * wv.y;
                acc[i][2] += av * wv.z; acc[i][3] += av * wv.w;
            }
        }
    }
#pragma unroll
    for (int i = 0; i < 8; i++) {
        ushort4 o;
        o.x = f2bf(acc[i][0]); o.y = f2bf(acc[i][1]);
        o.z = f2bf(acc[i][2]); o.w = f2bf(acc[i][3]);
        *(ushort4*)&sup[(rowbase + rg * 8 + i) * 128 + jg * 4] = o;
    }
}

// ---------- gather-reduce: wave per node, 2 dims per lane ----------
__global__ __launch_bounds__(256) void k_gather(const int2* __restrict__ edges,
                         const int* __restrict__ offs,
                         const int* __restrict__ ends,
                         const unsigned short* __restrict__ sup,
                         const float* __restrict__ bias,
                         unsigned short* __restrict__ cur) {
    int bn = blockIdx.x * 4 + (threadIdx.x >> 6);     // t*NN + n, wave-uniform
    bn = __builtin_amdgcn_readfirstlane(bn);
    int t = bn >> 14;
    int l = threadIdx.x & 63;
    int beg = offs[bn];
    int end = ends[bn];
    const unsigned short* supt = sup + (size_t)t * NN * 128;
    const int2* eg = edges + (size_t)t * EE;
    float acc0 = 0.f, acc1 = 0.f;                     // dims 2l, 2l+1
    int p = beg;
    for (; p + 3 < end; p += 4) {
        int2 e0 = eg[p], e1 = eg[p + 1], e2 = eg[p + 2], e3 = eg[p + 3];
        unsigned int u0 = *(const unsigned int*)&supt[(size_t)e0.x * 128 + 2 * l];
        unsigned int u1 = *(const unsigned int*)&supt[(size_t)e1.x * 128 + 2 * l];
        unsigned int u2 = *(const unsigned int*)&supt[(size_t)e2.x * 128 + 2 * l];
        unsigned int u3 = *(const unsigned int*)&supt[(size_t)e3.x * 128 + 2 * l];
        float w0 = __int_as_float(e0.y), w1 = __int_as_float(e1.y);
        float w2 = __int_as_float(e2.y), w3 = __int_as_float(e3.y);
        acc0 += w0 * bf2f((unsigned short)u0); acc1 += w0 * bf2f((unsigned short)(u0 >> 16));
        acc0 += w1 * bf2f((unsigned short)u1); acc1 += w1 * bf2f((unsigned short)(u1 >> 16));
        acc0 += w2 * bf2f((unsigned short)u2); acc1 += w2 * bf2f((unsigned short)(u2 >> 16));
        acc0 += w3 * bf2f((unsigned short)u3); acc1 += w3 * bf2f((unsigned short)(u3 >> 16));
    }
    for (; p < end; p++) {
        int2 e0 = eg[p];
        unsigned int u0 = *(const unsigned int*)&supt[(size_t)e0.x * 128 + 2 * l];
        float w0 = __int_as_float(e0.y);
        acc0 += w0 * bf2f((unsigned short)u0);
        acc1 += w0 * bf2f((unsigned short)(u0 >> 16));
    }
    float r0 = acc0 + bias[2 * l];
    float r1 = acc1 + bias[2 * l + 1];
    ushort2 o;
    o.x = f2bf(r0 > 0.f ? r0 : 0.f);
    o.y = f2bf(r1 > 0.f ? r1 : 0.f);
    *(ushort2*)&cur[(size_t)bn * 128 + 2 * l] = o;
}

// ---------- gates_x = cur @ w_ih^T + (b_ih+b_hh), bf16 MFMA ----------
// grid 3072, 256 thr. A-tile (64 rows of cur) staged ONCE; loop gb=0..7 over
// gate-blocks (B-tile re-staged from L2-resident wih). Saves 8x re-read of cur.
// Output layout for k_lstm: slot = j*4 + gate_idx (gate_idx = gcol>>7, j=gcol&127)
__global__ __launch_bounds__(256) void k_xgates(const unsigned short* __restrict__ cur,
                                                const float* __restrict__ wih,
                                                const float* __restrict__ bih,
                                                const float* __restrict__ bhh,
                                                unsigned short* __restrict__ gx) {
    __shared__ __align__(16) unsigned short At[64][136];   // +8 pad: 2-way banks
    __shared__ __align__(16) unsigned short Bt[64][136];
    int tid = threadIdx.x;
    size_t rowbase = (size_t)blockIdx.x * 64;
    // A tile: 64x128 bf16, 16B chunks (staged once)
#pragma unroll
    for (int q = 0; q < 4; q++) {
        int idx = tid + q * 256;          // 0..1023 (16 chunks per row)
        int r = idx >> 4;
        int cc = (idx & 15) * 8;
        *(ushortx8*)&At[r][cc] = *(const ushortx8*)&cur[(rowbase + r) * 128 + cc];
    }
    int wave = tid >> 6, lane = tid & 63;
    int m0 = wave * 16;
    int rin = lane & 15;
    int koff = (lane >> 4) * 8;
    int rq = (lane >> 4) * 4;
    for (int gb = 0; gb < 8; gb++) {
        int gbase = gb * 64;
        // B tile: wih rows gbase..gbase+64 (L2-hot), fp32 -> bf16
#pragma unroll
        for (int q = 0; q < 8; q++) {
            int idx = tid + q * 256;      // 0..2047 (32 float4 per row)
            int r = idx >> 5;
            int c4 = (idx & 31) * 4;
            float4 v = *(const float4*)&wih[(size_t)(gbase + r) * 128 + c4];
            ushort4 o;
            o.x = f2bf(v.x); o.y = f2bf(v.y); o.z = f2bf(v.z); o.w = f2bf(v.w);
            *(ushort4*)&Bt[r][c4] = o;
        }
        __syncthreads();
        floatx4 acc[4];
#pragma unroll
        for (int n = 0; n < 4; n++) acc[n] = (floatx4){0.f, 0.f, 0.f, 0.f};
#pragma unroll
        for (int kc = 0; kc < 4; kc++) {
            bf16x8 a = *(const bf16x8*)&At[m0 + rin][kc * 32 + koff];
#pragma unroll
            for (int n = 0; n < 4; n++) {
                bf16x8 b = *(const bf16x8*)&Bt[n * 16 + rin][kc * 32 + koff];
                acc[n] = __builtin_amdgcn_mfma_f32_16x16x32_bf16(a, b, acc[n], 0, 0, 0);
            }
        }
        // C/D: col = lane&15, row = (lane>>4)*4 + reg
#pragma unroll
        for (int n = 0; n < 4; n++) {
            int gcol = gbase + n * 16 + rin;
            float bs = bih[gcol] + bhh[gcol];
            int slot = ((gcol & 127) << 2) | (gcol >> 7);
#pragma unroll
            for (int i = 0; i < 4; i++) {
                size_t row = rowbase + m0 + rq + i;
                gx[row * 512 + slot] = f2bf(acc[n][i] + bs);
            }
        }
        __syncthreads();                  // all reads of Bt done before restage
    }
}

// ---------- persistent LSTM: 64 blocks x 512 thr, MFMA recurrent matvec ----
// Same structure as R5 (broadcast-A MFMA, col=lane&15, kg-redundant), but:
//  * gate-INTERLEAVED schedule: each gate's 4-MFMA chain split into two
//    depth-2 chains; its activation issues on the VALU while the NEXT
//    gate's MFMAs occupy the matrix pipe (pipes overlap instead of
//    phase-alternating). Gate order i,f,g first; c-update + tanh(c)
//    overlap gate-o's chain.
//  * x-gate bias folded into MFMA C-operand (acc init = {px,0,0,0}).
//  * gx ring prefetch WITHOUT end-clamp: gx sits at ws+0 and cur directly
//    after it, so reading 3 steps past the end lands in allocated memory.
__global__ __launch_bounds__(512, 2) void k_lstm(const unsigned short* __restrict__ gx,
                                                 const float* __restrict__ whh,
                                                 const float* __restrict__ h0,
                                                 const float* __restrict__ c0,
                                                 float* __restrict__ out) {
    __shared__ __align__(16) _Float16 hsh[2][128];   // double-buffered h (f16)
    int b = blockIdx.x, tid = threadIdx.x;
    int w = tid >> 6;                 // wave 0..7
    int l = tid & 63;
    int col = l & 15;                 // element within wave's 16
    int kg = l >> 4;                  // k-group 0..3 (8 k each per K-tile)
    int j = w * 16 + col;             // owned element (x4 redundant over kg)

    // B fragments: bw[n][kt], row = n*128 + j, k = kt*32 + kg*8 + i
    f16x8 bw[4][4];
#pragma unroll
    for (int n = 0; n < 4; n++) {
        const float* rp = whh + (size_t)(n * 128 + j) * 128;
#pragma unroll
        for (int kt = 0; kt < 4; kt++) {
            int k0 = kt * 32 + kg * 8;
            float4 v0 = *(const float4*)(rp + k0);
            float4 v1 = *(const float4*)(rp + k0 + 4);
            f16x8 f;
            f[0] = (_Float16)v0.x; f[1] = (_Float16)v0.y;
            f[2] = (_Float16)v0.z; f[3] = (_Float16)v0.w;
            f[4] = (_Float16)v1.x; f[5] = (_Float16)v1.y;
            f[6] = (_Float16)v1.z; f[7] = (_Float16)v1.w;
            bw[n][kt] = f;
        }
    }
    float c = c0[(size_t)b * 128 + j];               // redundant across kg
    if (tid < 128) hsh[0][tid] = (_Float16)h0[(size_t)b * 128 + tid];
    __syncthreads();

    // gx ring: one uint2 (4 bf16: i,f,g,o of element j) per step, 3 deep
    const unsigned short* gxb = gx + (size_t)b * 512 + 4 * j;
    uint2 rg0 = *(const uint2*)(gxb);
    uint2 rg1 = *(const uint2*)(gxb + 32768);
    uint2 rg2 = *(const uint2*)(gxb + 2 * (size_t)32768);

#define MF(a, bfrag, acc) __builtin_amdgcn_mfma_f32_16x16x32_f16(a, bfrag, acc, 0, 0, 0)

#define LSTM_STEP(T, RD, WR, QIDX)                                          \
    {                                                                       \
        f16x8 a0_ = *(const f16x8*)&hsh[RD][kg * 8];                        \
        f16x8 a1_ = *(const f16x8*)&hsh[RD][32 + kg * 8];                   \
        f16x8 a2_ = *(const f16x8*)&hsh[RD][64 + kg * 8];                   \
        f16x8 a3_ = *(const f16x8*)&hsh[RD][96 + kg * 8];                   \
        float px0_ = bf2f((unsigned short)(rg0.x & 0xffffu));               \
        float px1_ = bf2f((unsigned short)(rg0.x >> 16));                   \
        float px2_ = bf2f((unsigned short)(rg0.y & 0xffffu));               \
        float px3_ = bf2f((unsigned short)(rg0.y >> 16));                   \
        floatx4 i0_ = (floatx4){px0_, 0.f, 0.f, 0.f};                       \
        floatx4 i1_ = (floatx4){0.f, 0.f, 0.f, 0.f};                        \
        i0_ = MF(a0_, bw[0][0], i0_); i1_ = MF(a1_, bw[0][1], i1_);         \
        i0_ = MF(a2_, bw[0][2], i0_); i1_ = MF(a3_, bw[0][3], i1_);         \
        floatx4 f0_ = (floatx4){px1_, 0.f, 0.f, 0.f};                       \
        floatx4 f1_ = (floatx4){0.f, 0.f, 0.f, 0.f};                        \
        f0_ = MF(a0_, bw[1][0], f0_); f1_ = MF(a1_, bw[1][1], f1_);         \
        f0_ = MF(a2_, bw[1][2], f0_); f1_ = MF(a3_, bw[1][3], f1_);         \
        float ai_ = fast_sig(i0_[0] + i1_[0]);                              \
        floatx4 g0_ = (floatx4){px2_, 0.f, 0.f, 0.f};                       \
        floatx4 g1_ = (floatx4){0.f, 0.f, 0.f, 0.f};                        \
        g0_ = MF(a0_, bw[2][0], g0_); g1_ = MF(a1_, bw[2][1], g1_);         \
        g0_ = MF(a2_, bw[2][2], g0_); g1_ = MF(a3_, bw[2][3], g1_);         \
        float af_ = fast_sig(f0_[0] + f1_[0]);                              \
        floatx4 o0_ = (floatx4){px3_, 0.f, 0.f, 0.f};                       \
        floatx4 o1_ = (floatx4){0.f, 0.f, 0.f, 0.f};                        \
        o0_ = MF(a0_, bw[3][0], o0_); o1_ = MF(a1_, bw[3][1], o1_);         \
        o0_ = MF(a2_, bw[3][2], o0_); o1_ = MF(a3_, bw[3][3], o1_);         \
        float ag_ = fast_tanh(g0_[0] + g1_[0]);                             \
        c = af_ * c + ai_ * ag_;                                            \
        float tc_ = fast_tanh(c);                                           \
        float ao_ = fast_sig(o0_[0] + o1_[0]);                              \
        float hn_ = ao_ * tc_;                                              \
        hh8[QIDX] = hn_;                                                    \
        if (kg == 0) hsh[WR][j] = (_Float16)hn_;                            \
        rg0 = rg1; rg1 = rg2;                                               \
        rg2 = *(const uint2*)(gxb + (size_t)((T) + 3) * 32768);             \
        __syncthreads();                                                    \
    }

    for (int t8 = 0; t8 < TT; t8 += 8) {
        float hh8[8];
        LSTM_STEP(t8 + 0, 0, 1, 0);
        LSTM_STEP(t8 + 1, 1, 0, 1);
        LSTM_STEP(t8 + 2, 0, 1, 2);
        LSTM_STEP(t8 + 3, 1, 0, 3);
        LSTM_STEP(t8 + 4, 0, 1, 4);
        LSTM_STEP(t8 + 5, 1, 0, 5);
        LSTM_STEP(t8 + 6, 0, 1, 6);
        LSTM_STEP(t8 + 7, 1, 0, 7);
        if (kg == 0) {
#pragma unroll
            for (int qq = 0; qq < 8; qq++)
                out[((size_t)(t8 + qq) * 64 + b) * 128 + j] = hh8[qq];
        }
    }
#undef LSTM_STEP
#undef MF
}

// ---------- launcher ----------
extern "C" void kernel_launch(void* const* d_in, const int* in_sizes, int n_in,
                              void* d_out, int out_size, void* d_ws, size_t ws_size,
                              hipStream_t stream) {
    const int* adj    = (const int*)d_in[0];
    const float* vals = (const float*)d_in[1];
    const float* xs   = (const float*)d_in[2];
    const float* gw   = (const float*)d_in[3];
    const float* gb   = (const float*)d_in[4];
    const float* wih  = (const float*)d_in[5];
    const float* whh  = (const float*)d_in[6];
    const float* bih  = (const float*)d_in[7];
    const float* bhh  = (const float*)d_in[8];
    const float* h0   = (const float*)d_in[9];
    const float* c0   = (const float*)d_in[10];
    float* out = (float*)d_out;

    // Workspace layout (251,658,240 B total):
    //   [0, 201,326,592)             gx (bf16, S*N*512)  -- k_lstm may read
    //                                up to 3 steps (~197 KB) past the end;
    //                                those reads land in the cur region.
    //   [201,326,592, 251,658,240)   cur (bf16, S*N*128)
    // Aliased INSIDE the gx region (all dead before k_xgates writes gx):
    //   sup @ 0 (50 MB), counts/offs/cursor/edges after it.
    char* ws = (char*)d_ws;
    unsigned short* gx  = (unsigned short*)(ws);
    unsigned short* cur = (unsigned short*)(ws + 201326592);
    unsigned short* sup = (unsigned short*)(ws);
    int* counts         = (int*)(ws + 50331648);
    int* offs           = (int*)(ws + 51118080);
    int* cursor         = (int*)(ws + 51904512);
    int2* edges         = (int2*)(ws + 52690944);

    k_zero<<<(SS * NN) / 256, 256, 0, stream>>>(counts);
    k_count<<<(SS * EE) / 256, 256, 0, stream>>>(adj, counts);
    k_scan<<<SS, 1024, 0, stream>>>(counts, offs, cursor);
    k_scatter<<<(SS * EE) / 256, 256, 0, stream>>>(adj, vals, cursor, edges);
    k_support<<<(SS * NN) / 64, 256, 0, stream>>>(xs, gw, sup);
    k_gather<<<(SS * NN) / 4, 256, 0, stream>>>(edges, offs, cursor, sup, gb, cur);
    k_xgates<<<(SS * NN) / 64, 256, 0, stream>>>(cur, wih, bih, bhh, gx);
    k_lstm<<<64, 512, 0, stream>>>(gx, whh, h0, c0, out);
}